// Round 3
// baseline (749.760 us; speedup 1.0000x reference)
//
#include <hip/hip_runtime.h>
#include <hip/hip_bf16.h>

typedef unsigned short u16;
typedef unsigned int u32;
typedef __attribute__((ext_vector_type(8))) short short8;
typedef __attribute__((ext_vector_type(4))) float f32x4;

#define NN 8192
#define NF 512
#define NH 256
#define RB 256          // row-blocks in conv_adj (32 rows each)
#define BKNZ 64         // K-step of the no-split adj GEMM (LDS = 72 KiB total)

__device__ __forceinline__ float bf2f(u32 u) {
  union { u32 i; float f; } v; v.i = u << 16; return v.f;
}
__device__ __forceinline__ u16 f2bf(float f) {
  union { __hip_bfloat16 b; u16 u; } v; v.b = __float2bfloat16(f); return v.u;
}
__device__ __forceinline__ u32 pack2(float a, float b) {
  return (u32)f2bf(a) | ((u32)f2bf(b) << 16);
}

// ---- adj fp32 -> bf16, fused row & col partial sums (atomic-free) ----
// grid (4, RB), 256 thr. Block (s, rb): cols s*2048 + t*8, rows rb*32..+32.
__global__ __launch_bounds__(256) void conv_adj_k(const float* __restrict__ adj,
                                                  u16* __restrict__ adjb,
                                                  float* __restrict__ rowsum_part,
                                                  float* __restrict__ colsum_part) {
  __shared__ float red[4][32];
  const int t = threadIdx.x;
  const int w = t >> 6, lane = t & 63;
  const int s = blockIdx.x;
  const int c0 = s * 2048 + t * 8;
  const int r0 = blockIdx.y * 32;
  float cp[8] = {0.f, 0.f, 0.f, 0.f, 0.f, 0.f, 0.f, 0.f};
  for (int r = 0; r < 32; ++r) {
    const size_t base = (size_t)(r0 + r) * NN + c0;
    float4 v0 = *(const float4*)(adj + base);
    float4 v1 = *(const float4*)(adj + base + 4);
    uint4 pk;
    pk.x = pack2(v0.x, v0.y); pk.y = pack2(v0.z, v0.w);
    pk.z = pack2(v1.x, v1.y); pk.w = pack2(v1.z, v1.w);
    *(uint4*)(adjb + base) = pk;
    cp[0] += v0.x; cp[1] += v0.y; cp[2] += v0.z; cp[3] += v0.w;
    cp[4] += v1.x; cp[5] += v1.y; cp[6] += v1.z; cp[7] += v1.w;
    float rs = (v0.x + v0.y) + (v0.z + v0.w) + ((v1.x + v1.y) + (v1.z + v1.w));
#pragma unroll
    for (int off = 32; off > 0; off >>= 1) rs += __shfl_down(rs, off, 64);
    if (lane == 0) red[w][r] = rs;
  }
  __syncthreads();
  if (t < 32)
    rowsum_part[(size_t)s * NN + r0 + t] =
        (red[0][t] + red[1][t]) + (red[2][t] + red[3][t]);
  float* cdst = colsum_part + (size_t)blockIdx.y * NN + c0;
  *(float4*)cdst = make_float4(cp[0], cp[1], cp[2], cp[3]);
  *(float4*)(cdst + 4) = make_float4(cp[4], cp[5], cp[6], cp[7]);
}

// ---- reduce partials -> drow/dcol = sums^-0.5 with 0-guard ----
__global__ __launch_bounds__(256) void reduce_sums_k(const float* __restrict__ rowp,
                                                     const float* __restrict__ colp,
                                                     float* __restrict__ drow,
                                                     float* __restrict__ dcol) {
  const int i = blockIdx.x * 256 + threadIdx.x;
  const float rs = (rowp[i] + rowp[NN + i]) + (rowp[2 * NN + i] + rowp[3 * NN + i]);
  drow[i] = (rs > 0.f) ? rsqrtf(rs) : 0.f;
  float cs = 0.f;
#pragma unroll 8
  for (int rb = 0; rb < RB; ++rb) cs += colp[(size_t)rb * NN + i];
  dcol[i] = (cs > 0.f) ? rsqrtf(cs) : 0.f;
}

// ---- fused: x fp32->bf16 (blocks 0..2047)  |  W1 transpose->bf16 (blocks 2048..2175) ----
__global__ __launch_bounds__(256) void convxw1_k(const float* __restrict__ x,
                                                 u16* __restrict__ xb,
                                                 const float* __restrict__ W1,
                                                 u16* __restrict__ W1t) {
  __shared__ float tile[32][33];
  if (blockIdx.x < 2048) {
    const size_t i = ((size_t)blockIdx.x * 256 + threadIdx.x) * 8;
    float4 v0 = *(const float4*)(x + i);
    float4 v1 = *(const float4*)(x + i + 4);
    uint4 pk;
    pk.x = pack2(v0.x, v0.y); pk.y = pack2(v0.z, v0.w);
    pk.z = pack2(v1.x, v1.y); pk.w = pack2(v1.z, v1.w);
    *(uint4*)(xb + i) = pk;
  } else {
    const int blk = blockIdx.x - 2048;       // 128 blocks: 8 (over NH) x 16 (over NF)
    const int tx = threadIdx.x & 31, ty = threadIdx.x >> 5;
    const int c0 = (blk & 7) * 32;           // over NH
    const int r0 = (blk >> 3) * 32;          // over NF
#pragma unroll
    for (int d = 0; d < 32; d += 8)
      tile[ty + d][tx] = W1[(size_t)(r0 + ty + d) * NH + c0 + tx];
    __syncthreads();
#pragma unroll
    for (int d = 0; d < 32; d += 8)
      W1t[(size_t)(c0 + ty + d) * NF + r0 + tx] = f2bf(tile[tx][ty + d]);
  }
}

// ---- MFMA GEMM, 128x128 tile, BK=32, double-buffered global_load_lds ----
// (kept for P = x@W1; K=512)
__device__ __forceinline__ void stage128(const u16* __restrict__ A, int lda,
                                         const u16* __restrict__ Bt, int ldb,
                                         int m0, int n0, int kk,
                                         u16* as_, u16* bs_, int tid) {
#pragma unroll
  for (int h = 0; h < 2; ++h) {
    const int slot = tid + h * 256;
    const int row = slot >> 2, kc = slot & 3;
    const u16* srcA = A + (size_t)(m0 + row) * lda + kk + kc * 8;
    __builtin_amdgcn_global_load_lds((const __attribute__((address_space(1))) void*)srcA,
                                     (__attribute__((address_space(3))) void*)(as_ + slot * 8),
                                     16, 0, 0);
    const u16* srcB = Bt + (size_t)(n0 + row) * ldb + kk + kc * 8;
    __builtin_amdgcn_global_load_lds((const __attribute__((address_space(1))) void*)srcB,
                                     (__attribute__((address_space(3))) void*)(bs_ + slot * 8),
                                     16, 0, 0);
  }
}

__global__ __launch_bounds__(256) void gemm_k(const u16* __restrict__ A, int lda,
                                              const u16* __restrict__ Bt, int ldb,
                                              int kChunk, float* __restrict__ out) {
  __shared__ __align__(16) u16 As[2][128 * 32];
  __shared__ __align__(16) u16 Bs[2][128 * 32];
  const int tid = threadIdx.x;
  const int w = tid >> 6, lane = tid & 63;
  const int lq = lane >> 4, lr = lane & 15;
  const int wr = (w >> 1) * 64, wc = (w & 1) * 64;
  const int n0 = blockIdx.x * 128;
  const int m0 = blockIdx.y * 128;
  const int kk0 = blockIdx.z * kChunk;
  const int nk = kChunk >> 5;

  f32x4 acc[4][4] = {};

  stage128(A, lda, Bt, ldb, m0, n0, kk0, As[0], Bs[0], tid);
  for (int kt = 0; kt < nk; ++kt) {
    const int cur = kt & 1;
    __syncthreads();  // drains vmcnt: buf 'cur' ready; buf '!cur' free
    if (kt + 1 < nk)
      stage128(A, lda, Bt, ldb, m0, n0, kk0 + ((kt + 1) << 5), As[cur ^ 1], Bs[cur ^ 1], tid);
    short8 a[4], b[4];
#pragma unroll
    for (int i = 0; i < 4; ++i)
      a[i] = *(const short8*)(As[cur] + (wr + i * 16 + lr) * 32 + lq * 8);
#pragma unroll
    for (int i = 0; i < 4; ++i)
      b[i] = *(const short8*)(Bs[cur] + (wc + i * 16 + lr) * 32 + lq * 8);
#pragma unroll
    for (int i = 0; i < 4; ++i)
#pragma unroll
      for (int j = 0; j < 4; ++j)
        acc[i][j] = __builtin_amdgcn_mfma_f32_16x16x32_bf16(a[i], b[j], acc[i][j], 0, 0, 0);
  }

  float* o = out + (size_t)blockIdx.z * ((size_t)NN * NH);
  // C/D layout: col = lane&15, row = (lane>>4)*4 + reg
#pragma unroll
  for (int i = 0; i < 4; ++i)
#pragma unroll
    for (int j = 0; j < 4; ++j) {
      const int gn = n0 + wc + j * 16 + lr;
      const int gm0 = m0 + wr + i * 16 + lq * 4;
#pragma unroll
      for (int r = 0; r < 4; ++r)
        o[(size_t)(gm0 + r) * NH + gn] = acc[i][j][r];
    }
}

// ---- no-split adj GEMM: out = drow .* (adjb @ Bt^T), full K=8192, fp32 acc ----
// BM=32, BN=NH=256. grid 256 blocks (1/CU), 512 thr = 8 waves, wave w: cols w*32.
// LDS 72 KiB double-buffered (A 8K, B 64K). XOR swizzle (rule 21): linear LDS
// dest, inverse-swizzled global SOURCE, swizzled ds_read.
// swz: element-chunk kc (mult of 8) -> kc ^ ((row&7)<<3), involution within a
// 64-elem (128 B) row; spreads the 16-lane same-column reads across 8 slots
// (2-way conflict = free, vs 16-way unswizzled).
__device__ __forceinline__ void stage_nz(const u16* __restrict__ A,
                                         const u16* __restrict__ Bt,
                                         int m0, int kk,
                                         u16* as_, u16* bs_, int tid) {
  if (tid < 256) {                              // A: 32 rows x 8 chunks = 256 slots
    const int row = tid >> 3, kc = (tid & 7) * 8;
    const int sc = kc ^ ((row & 7) << 3);
    const u16* srcA = A + (size_t)(m0 + row) * NN + kk + sc;
    __builtin_amdgcn_global_load_lds((const __attribute__((address_space(1))) void*)srcA,
                                     (__attribute__((address_space(3))) void*)(as_ + tid * 8),
                                     16, 0, 0);
  }
#pragma unroll
  for (int h = 0; h < 4; ++h) {                 // B: 256 rows x 8 chunks = 2048 slots
    const int slot = tid + h * 512;
    const int row = slot >> 3, kc = (slot & 7) * 8;
    const int sc = kc ^ ((row & 7) << 3);
    const u16* srcB = Bt + (size_t)row * NN + kk + sc;
    __builtin_amdgcn_global_load_lds((const __attribute__((address_space(1))) void*)srcB,
                                     (__attribute__((address_space(3))) void*)(bs_ + slot * 8),
                                     16, 0, 0);
  }
}

__global__ __launch_bounds__(512) void gemm_nz_k(const u16* __restrict__ A,
                                                 const u16* __restrict__ Bt,
                                                 const float* __restrict__ drow,
                                                 float* __restrict__ out) {
  __shared__ __align__(16) u16 As[2][32 * BKNZ];    // 4 KiB x2
  __shared__ __align__(16) u16 Bs[2][256 * BKNZ];   // 32 KiB x2
  const int tid = threadIdx.x;
  const int w = tid >> 6, lane = tid & 63;
  const int lq = lane >> 4, lr = lane & 15;
  const int wc = w * 32;
  const int m0 = blockIdx.x * 32;

  f32x4 acc[2][2] = {};

  stage_nz(A, Bt, m0, 0, As[0], Bs[0], tid);
  const int nk = NN / BKNZ;  // 128
  for (int kt = 0; kt < nk; ++kt) {
    const int cur = kt & 1;
    __syncthreads();  // drains vmcnt: buf 'cur' ready; buf '!cur' free
    if (kt + 1 < nk)
      stage_nz(A, Bt, m0, (kt + 1) * BKNZ, As[cur ^ 1], Bs[cur ^ 1], tid);
#pragma unroll
    for (int kk2 = 0; kk2 < BKNZ / 32; ++kk2) {   // 2
      short8 a[2], b[2];
#pragma unroll
      for (int i = 0; i < 2; ++i) {
        const int ar = i * 16 + lr;
        const int sa = (kk2 * 32 + lq * 8) ^ ((ar & 7) << 3);
        a[i] = *(const short8*)(As[cur] + ar * BKNZ + sa);
      }
#pragma unroll
      for (int j = 0; j < 2; ++j) {
        const int br = wc + j * 16 + lr;
        const int sb = (kk2 * 32 + lq * 8) ^ ((br & 7) << 3);
        b[j] = *(const short8*)(Bs[cur] + br * BKNZ + sb);
      }
#pragma unroll
      for (int i = 0; i < 2; ++i)
#pragma unroll
        for (int j = 0; j < 2; ++j)
          acc[i][j] = __builtin_amdgcn_mfma_f32_16x16x32_bf16(a[i], b[j], acc[i][j], 0, 0, 0);
    }
  }

  // C/D layout: col = lane&15, row = (lane>>4)*4 + reg;  out scaled by drow[row]
#pragma unroll
  for (int i = 0; i < 2; ++i)
#pragma unroll
    for (int j = 0; j < 2; ++j) {
      const int gn = wc + j * 16 + lr;
      const int gm0 = m0 + i * 16 + lq * 4;
#pragma unroll
      for (int r = 0; r < 4; ++r)
        out[(size_t)(gm0 + r) * NH + gn] = drow[gm0 + r] * acc[i][j][r];
    }
}

// ---- Bt = (d_col .* S)^T as bf16  (used for B1t from P and B2t from Q1) ----
__global__ __launch_bounds__(256) void t1_k(const float* __restrict__ S,
                                            const float* __restrict__ dcol,
                                            u16* __restrict__ Bt) {
  __shared__ float tile[32][33];
  const int tx = threadIdx.x & 31, ty = threadIdx.x >> 5;
  const int c0 = blockIdx.x * 32;  // over NH
  const int r0 = blockIdx.y * 32;  // over NN
#pragma unroll
  for (int d = 0; d < 32; d += 8) {
    const int rr = r0 + ty + d;
    tile[ty + d][tx] = dcol[rr] * S[(size_t)rr * NH + c0 + tx];
  }
  __syncthreads();
#pragma unroll
  for (int d = 0; d < 32; d += 8)
    Bt[(size_t)(c0 + ty + d) * NN + r0 + tx] = f2bf(tile[tx][ty + d]);
}

// ---- fused: h = relu(0.5P - 0.5Q1 - Hs) in-reg; R = h@W2; B3 = d_col .* R ----
// grid NN/4 blocks, 256 thr; wave w handles row i = bid*4 + w (lane covers 4 cols).
__global__ __launch_bounds__(256) void r3r_k(const float* __restrict__ Hs,
                                             const float* __restrict__ P,
                                             const float* __restrict__ Q1,
                                             const float* __restrict__ W2,
                                             const float* __restrict__ dcol,
                                             float* __restrict__ R,
                                             float* __restrict__ B3) {
  const int w = threadIdx.x >> 6, lane = threadIdx.x & 63;
  const int i = blockIdx.x * 4 + w;
  const size_t base = (size_t)i * NH + lane * 4;
  float4 p = *(const float4*)(P + base);
  float4 q = *(const float4*)(Q1 + base);
  float4 s = *(const float4*)(Hs + base);
  const float h0 = fmaxf(0.5f * p.x - 0.5f * q.x - s.x, 0.f);
  const float h1 = fmaxf(0.5f * p.y - 0.5f * q.y - s.y, 0.f);
  const float h2 = fmaxf(0.5f * p.z - 0.5f * q.z - s.z, 0.f);
  const float h3 = fmaxf(0.5f * p.w - 0.5f * q.w - s.w, 0.f);
  float4 w01 = *(const float4*)(W2 + lane * 8);
  float4 w23 = *(const float4*)(W2 + lane * 8 + 4);
  float a0 = h0 * w01.x + h1 * w01.z + h2 * w23.x + h3 * w23.z;
  float a1 = h0 * w01.y + h1 * w01.w + h2 * w23.y + h3 * w23.w;
#pragma unroll
  for (int off = 32; off > 0; off >>= 1) {
    a0 += __shfl_down(a0, off, 64);
    a1 += __shfl_down(a1, off, 64);
  }
  if (lane == 0) {
    R[i * 2] = a0;
    R[i * 2 + 1] = a1;
    const float dc = dcol[i];
    B3[i * 2] = dc * a0;
    B3[i * 2 + 1] = dc * a1;
  }
}

// ---- row GEMV over adjb (bf16) with 2-wide fp32 B; fused epilogues ----
__global__ __launch_bounds__(256) void gemv_k(
    const u16* __restrict__ adjb, const float* __restrict__ B,
    const float* __restrict__ drow, const float* __restrict__ dcol,
    const float* __restrict__ Rin, const float* __restrict__ S1in,
    const float* __restrict__ b2, float* __restrict__ S1out,
    float* __restrict__ B4, float* __restrict__ outp, int mode) {
  const int i = blockIdx.x;
  const int t = threadIdx.x;
  float a0 = 0.f, a1 = 0.f;
#pragma unroll
  for (int c = 0; c < 4; ++c) {
    const int col = c * 2048 + t * 8;
    uint4 av = *(const uint4*)(adjb + (size_t)i * NN + col);
    const u32* aw = (const u32*)&av;
    float bv[16];
    *(float4*)(bv) = *(const float4*)(B + col * 2);
    *(float4*)(bv + 4) = *(const float4*)(B + col * 2 + 4);
    *(float4*)(bv + 8) = *(const float4*)(B + col * 2 + 8);
    *(float4*)(bv + 12) = *(const float4*)(B + col * 2 + 12);
#pragma unroll
    for (int j = 0; j < 8; ++j) {
      const u32 a = aw[j >> 1];
      const float aval = bf2f((j & 1) ? (a >> 16) : (a & 0xffffu));
      a0 += aval * bv[2 * j];
      a1 += aval * bv[2 * j + 1];
    }
  }
#pragma unroll
  for (int off = 32; off > 0; off >>= 1) {
    a0 += __shfl_down(a0, off, 64);
    a1 += __shfl_down(a1, off, 64);
  }
  __shared__ float red[8];
  const int w = t >> 6, lane = t & 63;
  if (lane == 0) { red[w] = a0; red[4 + w] = a1; }
  __syncthreads();
  if (t == 0) {
    float s0 = (red[0] + red[1]) + (red[2] + red[3]);
    float s1 = (red[4] + red[5]) + (red[6] + red[7]);
    const float dr = drow[i];
    s0 *= dr; s1 *= dr;
    if (mode == 0) {  // S1 = d_row .* (adj@B3); B4 = d_col .* S1
      S1out[i * 2] = s0;
      S1out[i * 2 + 1] = s1;
      const float dc = dcol[i];
      B4[i * 2] = dc * s0;
      B4[i * 2 + 1] = dc * s1;
    } else {  // logits = 0.5R - 0.5S1 - S2 + b2; log_softmax
      const float l0 = 0.5f * Rin[i * 2] - 0.5f * S1in[i * 2] - s0 + b2[0];
      const float l1 = 0.5f * Rin[i * 2 + 1] - 0.5f * S1in[i * 2 + 1] - s1 + b2[1];
      const float m = fmaxf(l0, l1);
      const float lse = m + logf(__expf(l0 - m) + __expf(l1 - m));
      outp[i * 2] = l0 - lse;
      outp[i * 2 + 1] = l1 - lse;
    }
  }
}

extern "C" void kernel_launch(void* const* d_in, const int* in_sizes, int n_in,
                              void* d_out, int out_size, void* d_ws, size_t ws_size,
                              hipStream_t stream) {
  (void)in_sizes; (void)n_in; (void)out_size; (void)ws_size;
  const float* x   = (const float*)d_in[0];
  const float* adj = (const float*)d_in[1];
  const float* W1  = (const float*)d_in[2];
  const float* W2  = (const float*)d_in[3];
  const float* b2  = (const float*)d_in[4];
  float* outp = (float*)d_out;

  char* ws = (char*)d_ws;
  size_t off = 0;
  auto alloc = [&](size_t bytes) -> char* {
    char* p = ws + off;
    off += (bytes + 255) & ~(size_t)255;
    return p;
  };
  u16* adjb  = (u16*)alloc((size_t)NN * NN * 2);             // 134 MB
  u16* xb    = (u16*)alloc((size_t)NN * NF * 2);             // 8.4 MB
  u16* W1t   = (u16*)alloc((size_t)NH * NF * 2);             // 0.26 MB
  float* rowp = (float*)alloc((size_t)4 * NN * 4);           // 128 KB
  float* colp = (float*)alloc((size_t)RB * NN * 4);          // 8 MB
  float* drow = (float*)alloc((size_t)NN * 4);
  float* dcol = (float*)alloc((size_t)NN * 4);
  float* P   = (float*)alloc((size_t)NN * NH * 4);           // 8.4 MB
  u16* B1t   = (u16*)alloc((size_t)NH * NN * 2);             // 4.2 MB
  float* Q1  = (float*)alloc((size_t)NN * NH * 4);           // 8.4 MB
  u16* B2t   = (u16*)alloc((size_t)NH * NN * 2);             // 4.2 MB
  float* Hs  = (float*)alloc((size_t)NN * NH * 4);           // 8.4 MB
  float* R   = (float*)alloc((size_t)NN * 2 * 4);
  float* B3  = (float*)alloc((size_t)NN * 2 * 4);
  float* S1  = (float*)alloc((size_t)NN * 2 * 4);
  float* B4  = (float*)alloc((size_t)NN * 2 * 4);

  conv_adj_k<<<dim3(4, RB), 256, 0, stream>>>(adj, adjb, rowp, colp);
  reduce_sums_k<<<NN / 256, 256, 0, stream>>>(rowp, colp, drow, dcol);
  convxw1_k<<<2176, 256, 0, stream>>>(x, xb, W1, W1t);

  // P = x@W1 (fp32 out)
  gemm_k<<<dim3(2, 64, 1), 256, 0, stream>>>(xb, NF, W1t, NF, NF, P);
  t1_k<<<dim3(8, 256), 256, 0, stream>>>(P, dcol, B1t);

  // Q1 = drow .* (adj @ B1)  -- full-K, no partials
  gemm_nz_k<<<256, 512, 0, stream>>>(adjb, B1t, drow, Q1);
  t1_k<<<dim3(8, 256), 256, 0, stream>>>(Q1, dcol, B2t);

  // Hs = drow .* (adj @ B2)
  gemm_nz_k<<<256, 512, 0, stream>>>(adjb, B2t, drow, Hs);

  // h = relu(0.5P - 0.5Q1 - Hs); R = h@W2; B3 = dcol .* R
  r3r_k<<<NN / 4, 256, 0, stream>>>(Hs, P, Q1, W2, dcol, R, B3);

  gemv_k<<<NN, 256, 0, stream>>>(adjb, B3, drow, dcol, nullptr, nullptr, nullptr, S1, B4, nullptr, 0);
  gemv_k<<<NN, 256, 0, stream>>>(adjb, B4, drow, dcol, R, S1, b2, nullptr, nullptr, outp, 1);
}

// Round 4
// 647.455 us; speedup vs baseline: 1.1580x; 1.1580x over previous
//
#include <hip/hip_runtime.h>
#include <hip/hip_bf16.h>

typedef unsigned short u16;
typedef unsigned int u32;
typedef __attribute__((ext_vector_type(8))) short short8;
typedef __attribute__((ext_vector_type(4))) float f32x4;

#define NN 8192
#define NF 512
#define NH 256
#define SPLITZ 8        // z-split for 256x256-tile adj GEMMs: 32*8 = 256 blocks = 1/CU
#define RB 256          // row-blocks in conv_adj (32 rows each)
#define BKR 32          // K-step of ring-pipelined adj GEMM (4 x 32KB LDS ring)

__device__ __forceinline__ float bf2f(u32 u) {
  union { u32 i; float f; } v; v.i = u << 16; return v.f;
}
__device__ __forceinline__ u16 f2bf(float f) {
  union { __hip_bfloat16 b; u16 u; } v; v.b = __float2bfloat16(f); return v.u;
}
__device__ __forceinline__ u32 pack2(float a, float b) {
  return (u32)f2bf(a) | ((u32)f2bf(b) << 16);
}

// ---- reduce partials -> drow/dcol = sums^-0.5 with 0-guard ----
__global__ __launch_bounds__(256) void reduce_sums_k(const float* __restrict__ rowp,
                                                     const float* __restrict__ colp,
                                                     float* __restrict__ drow,
                                                     float* __restrict__ dcol) {
  const int i = blockIdx.x * 256 + threadIdx.x;
  const float rs = (rowp[i] + rowp[NN + i]) + (rowp[2 * NN + i] + rowp[3 * NN + i]);
  drow[i] = (rs > 0.f) ? rsqrtf(rs) : 0.f;
  float cs = 0.f;
#pragma unroll 8
  for (int rb = 0; rb < RB; ++rb) cs += colp[(size_t)rb * NN + i];
  dcol[i] = (cs > 0.f) ? rsqrtf(cs) : 0.f;
}

// ---- fused: x fp32->bf16 (blocks 0..2047)  |  W1 transpose->bf16 (blocks 2048..2175) ----
__global__ __launch_bounds__(256) void convxw1_k(const float* __restrict__ x,
                                                 u16* __restrict__ xb,
                                                 const float* __restrict__ W1,
                                                 u16* __restrict__ W1t) {
  __shared__ float tile[32][33];
  if (blockIdx.x < 2048) {
    const size_t i = ((size_t)blockIdx.x * 256 + threadIdx.x) * 8;
    float4 v0 = *(const float4*)(x + i);
    float4 v1 = *(const float4*)(x + i + 4);
    uint4 pk;
    pk.x = pack2(v0.x, v0.y); pk.y = pack2(v0.z, v0.w);
    pk.z = pack2(v1.x, v1.y); pk.w = pack2(v1.z, v1.w);
    *(uint4*)(xb + i) = pk;
  } else {
    const int blk = blockIdx.x - 2048;       // 128 blocks: 8 (over NH) x 16 (over NF)
    const int tx = threadIdx.x & 31, ty = threadIdx.x >> 5;
    const int c0 = (blk & 7) * 32;           // over NH
    const int r0 = (blk >> 3) * 32;          // over NF
#pragma unroll
    for (int d = 0; d < 32; d += 8)
      tile[ty + d][tx] = W1[(size_t)(r0 + ty + d) * NH + c0 + tx];
    __syncthreads();
#pragma unroll
    for (int d = 0; d < 32; d += 8)
      W1t[(size_t)(c0 + ty + d) * NF + r0 + tx] = f2bf(tile[tx][ty + d]);
  }
}

// ---- stage for the 128x128 P-GEMM section ----
__device__ __forceinline__ void stage128(const u16* __restrict__ A, int lda,
                                         const u16* __restrict__ Bt, int ldb,
                                         int m0, int n0, int kk,
                                         u16* as_, u16* bs_, int tid) {
#pragma unroll
  for (int h = 0; h < 2; ++h) {
    const int slot = tid + h * 256;
    const int row = slot >> 2, kc = slot & 3;
    const u16* srcA = A + (size_t)(m0 + row) * lda + kk + kc * 8;
    __builtin_amdgcn_global_load_lds((const __attribute__((address_space(1))) void*)srcA,
                                     (__attribute__((address_space(3))) void*)(as_ + slot * 8),
                                     16, 0, 0);
    const u16* srcB = Bt + (size_t)(n0 + row) * ldb + kk + kc * 8;
    __builtin_amdgcn_global_load_lds((const __attribute__((address_space(1))) void*)srcB,
                                     (__attribute__((address_space(3))) void*)(bs_ + slot * 8),
                                     16, 0, 0);
  }
}

// ---- mega kernel: blocks 0..1023 = conv_adj (fp32->bf16 + row/col sums);
//      blocks 1024..1151 = P = xb@W1t (128x128 MFMA GEMM, K=512).
//      Independent workloads; P rides under conv_adj's HBM shadow. ----
__global__ __launch_bounds__(256) void mega_k(const float* __restrict__ adj,
                                              u16* __restrict__ adjb,
                                              float* __restrict__ rowsum_part,
                                              float* __restrict__ colsum_part,
                                              const u16* __restrict__ xb,
                                              const u16* __restrict__ W1t,
                                              float* __restrict__ P) {
  __shared__ float red[4][32];
  __shared__ __align__(16) u16 As[2][128 * 32];
  __shared__ __align__(16) u16 Bs[2][128 * 32];
  const int tid = threadIdx.x;
  if (blockIdx.x < 1024) {
    // ---- conv_adj section ----
    const int t = tid;
    const int w = t >> 6, lane = t & 63;
    const int s = blockIdx.x & 3;
    const int c0 = s * 2048 + t * 8;
    const int r0 = (blockIdx.x >> 2) * 32;
    float cp[8] = {0.f, 0.f, 0.f, 0.f, 0.f, 0.f, 0.f, 0.f};
    for (int r = 0; r < 32; ++r) {
      const size_t base = (size_t)(r0 + r) * NN + c0;
      float4 v0 = *(const float4*)(adj + base);
      float4 v1 = *(const float4*)(adj + base + 4);
      uint4 pk;
      pk.x = pack2(v0.x, v0.y); pk.y = pack2(v0.z, v0.w);
      pk.z = pack2(v1.x, v1.y); pk.w = pack2(v1.z, v1.w);
      *(uint4*)(adjb + base) = pk;
      cp[0] += v0.x; cp[1] += v0.y; cp[2] += v0.z; cp[3] += v0.w;
      cp[4] += v1.x; cp[5] += v1.y; cp[6] += v1.z; cp[7] += v1.w;
      float rs = (v0.x + v0.y) + (v0.z + v0.w) + ((v1.x + v1.y) + (v1.z + v1.w));
#pragma unroll
      for (int off = 32; off > 0; off >>= 1) rs += __shfl_down(rs, off, 64);
      if (lane == 0) red[w][r] = rs;
    }
    __syncthreads();
    if (t < 32)
      rowsum_part[(size_t)s * NN + r0 + t] =
          (red[0][t] + red[1][t]) + (red[2][t] + red[3][t]);
    float* cdst = colsum_part + (size_t)(blockIdx.x >> 2) * NN + c0;
    *(float4*)cdst = make_float4(cp[0], cp[1], cp[2], cp[3]);
    *(float4*)(cdst + 4) = make_float4(cp[4], cp[5], cp[6], cp[7]);
  } else {
    // ---- P = xb @ W1t^T section (128x128 tile, K=512) ----
    const int blk = blockIdx.x - 1024;
    const int w = tid >> 6, lane = tid & 63;
    const int lq = lane >> 4, lr = lane & 15;
    const int wr = (w >> 1) * 64, wc = (w & 1) * 64;
    const int n0 = (blk & 1) * 128;
    const int m0 = (blk >> 1) * 128;
    const int nk = NF >> 5;  // 16

    f32x4 acc[4][4] = {};

    stage128(xb, NF, W1t, NF, m0, n0, 0, As[0], Bs[0], tid);
    for (int kt = 0; kt < nk; ++kt) {
      const int cur = kt & 1;
      __syncthreads();
      if (kt + 1 < nk)
        stage128(xb, NF, W1t, NF, m0, n0, (kt + 1) << 5, As[cur ^ 1], Bs[cur ^ 1], tid);
      short8 a[4], b[4];
#pragma unroll
      for (int i = 0; i < 4; ++i)
        a[i] = *(const short8*)(As[cur] + (wr + i * 16 + lr) * 32 + lq * 8);
#pragma unroll
      for (int i = 0; i < 4; ++i)
        b[i] = *(const short8*)(Bs[cur] + (wc + i * 16 + lr) * 32 + lq * 8);
#pragma unroll
      for (int i = 0; i < 4; ++i)
#pragma unroll
        for (int j = 0; j < 4; ++j)
          acc[i][j] = __builtin_amdgcn_mfma_f32_16x16x32_bf16(a[i], b[j], acc[i][j], 0, 0, 0);
    }
    // C/D layout: col = lane&15, row = (lane>>4)*4 + reg
#pragma unroll
    for (int i = 0; i < 4; ++i)
#pragma unroll
      for (int j = 0; j < 4; ++j) {
        const int gn = n0 + wc + j * 16 + lr;
        const int gm0 = m0 + wr + i * 16 + lq * 4;
#pragma unroll
        for (int r = 0; r < 4; ++r)
          P[(size_t)(gm0 + r) * NH + gn] = acc[i][j][r];
      }
  }
}

// ---- ring-pipelined 256x256-tile adj GEMM, BK=32, 4-buffer counted-vmcnt ----
// grid (32 m-tiles, SPLITZ z), 512 thr = 8 waves (2M x 4N), per-wave 128x64.
// LDS 128 KiB (4 x {A 16K + B 16K}). Depth-3 prefetch: vmcnt(8) steady state,
// never 0 in main loop (T4). XOR swizzle c16 ^= (row&3): inverse-swizzled
// global SOURCE + swizzled ds_read (rule 21; pattern HW-verified round 3).
__device__ __forceinline__ void stage_r(const u16* __restrict__ A,
                                        const u16* __restrict__ Bt,
                                        int m0, int kk,
                                        u16* as_, u16* bs_, int tid) {
#pragma unroll
  for (int h = 0; h < 2; ++h) {
    const int slot = tid + h * 512;             // 1024 slots: 256 rows x 4 chunks(16B)
    const int row = slot >> 2, c16 = slot & 3;
    const int sc16 = c16 ^ (row & 3);
    const u16* srcA = A + (size_t)(m0 + row) * NN + kk + sc16 * 8;
    __builtin_amdgcn_global_load_lds((const __attribute__((address_space(1))) void*)srcA,
                                     (__attribute__((address_space(3))) void*)(as_ + slot * 8),
                                     16, 0, 0);
    const u16* srcB = Bt + (size_t)row * NN + kk + sc16 * 8;
    __builtin_amdgcn_global_load_lds((const __attribute__((address_space(1))) void*)srcB,
                                     (__attribute__((address_space(3))) void*)(bs_ + slot * 8),
                                     16, 0, 0);
  }
}

__global__ __launch_bounds__(512, 2) void gemm256r_k(const u16* __restrict__ A,
                                                     const u16* __restrict__ Bt,
                                                     int kChunk,
                                                     float* __restrict__ out) {
  __shared__ __align__(16) u16 As[4][256 * BKR];   // 16 KiB x4
  __shared__ __align__(16) u16 Bs[4][256 * BKR];   // 16 KiB x4
  const int tid = threadIdx.x;
  const int w = tid >> 6, lane = tid & 63;
  const int lq = lane >> 4, lr = lane & 15;
  const int wr = (w >> 2) * 128;   // 0 / 128
  const int wc = (w & 3) * 64;     // 0 / 64 / 128 / 192
  const int m0 = blockIdx.x * 256;
  const int kk0 = blockIdx.y * kChunk;
  const int nk = kChunk / BKR;     // 32

  f32x4 acc[8][4] = {};

  // prologue: fill 3 ring slots (12 loads/thread outstanding)
  stage_r(A, Bt, m0, kk0, As[0], Bs[0], tid);
  stage_r(A, Bt, m0, kk0 + BKR, As[1], Bs[1], tid);
  stage_r(A, Bt, m0, kk0 + 2 * BKR, As[2], Bs[2], tid);

  for (int kt = 0; kt < nk; ++kt) {
    // wait until stage kt's 4 loads (oldest) retired; loads for kt+1/kt+2 stay in flight
    if (kt + 2 < nk)      asm volatile("s_waitcnt vmcnt(8)" ::: "memory");
    else if (kt + 1 < nk) asm volatile("s_waitcnt vmcnt(4)" ::: "memory");
    else                  asm volatile("s_waitcnt vmcnt(0)" ::: "memory");
    __builtin_amdgcn_s_barrier();          // all threads' stage-kt data now in LDS
    __builtin_amdgcn_sched_barrier(0);
    if (kt + 3 < nk)                       // clobbers buf (kt-1)&3: reads done pre-barrier
      stage_r(A, Bt, m0, kk0 + (kt + 3) * BKR, As[(kt + 3) & 3], Bs[(kt + 3) & 3], tid);
    const u16* as_ = As[kt & 3];
    const u16* bs_ = Bs[kt & 3];
    short8 a[8], b[4];
#pragma unroll
    for (int i = 0; i < 8; ++i) {
      const int ar = wr + i * 16 + lr;
      a[i] = *(const short8*)(as_ + ar * BKR + ((lq ^ (ar & 3)) << 3));
    }
#pragma unroll
    for (int j = 0; j < 4; ++j) {
      const int br = wc + j * 16 + lr;
      b[j] = *(const short8*)(bs_ + br * BKR + ((lq ^ (br & 3)) << 3));
    }
    __builtin_amdgcn_s_setprio(1);
#pragma unroll
    for (int i = 0; i < 8; ++i)
#pragma unroll
      for (int j = 0; j < 4; ++j)
        acc[i][j] = __builtin_amdgcn_mfma_f32_16x16x32_bf16(a[i], b[j], acc[i][j], 0, 0, 0);
    __builtin_amdgcn_s_setprio(0);
  }

  float* o = out + (size_t)blockIdx.y * ((size_t)NN * NH);
  // C/D layout: col = lane&15, row = (lane>>4)*4 + reg
#pragma unroll
  for (int i = 0; i < 8; ++i)
#pragma unroll
    for (int j = 0; j < 4; ++j) {
      const int gn = wc + j * 16 + lr;
      const int gm0 = m0 + wr + i * 16 + lq * 4;
#pragma unroll
      for (int r = 0; r < 4; ++r)
        o[(size_t)(gm0 + r) * NH + gn] = acc[i][j][r];
    }
}

// ---- Bt = (d_col .* S)^T as bf16 ----
__global__ __launch_bounds__(256) void t1_k(const float* __restrict__ S,
                                            const float* __restrict__ dcol,
                                            u16* __restrict__ Bt) {
  __shared__ float tile[32][33];
  const int tx = threadIdx.x & 31, ty = threadIdx.x >> 5;
  const int c0 = blockIdx.x * 32;  // over NH
  const int r0 = blockIdx.y * 32;  // over NN
#pragma unroll
  for (int d = 0; d < 32; d += 8) {
    const int rr = r0 + ty + d;
    tile[ty + d][tx] = dcol[rr] * S[(size_t)rr * NH + c0 + tx];
  }
  __syncthreads();
#pragma unroll
  for (int d = 0; d < 32; d += 8)
    Bt[(size_t)(c0 + ty + d) * NN + r0 + tx] = f2bf(tile[tx][ty + d]);
}

// ---- reduce SPLITZ partials -> Q1 (fp32) and B2t = (d_col .* Q1)^T (bf16) ----
__global__ __launch_bounds__(256) void r2_k(const float* __restrict__ Qp,
                                            const float* __restrict__ drow,
                                            const float* __restrict__ dcol,
                                            float* __restrict__ Q1,
                                            u16* __restrict__ B2t) {
  __shared__ float tile[32][33];
  const int tx = threadIdx.x & 31, ty = threadIdx.x >> 5;
  const int c0 = blockIdx.x * 32;
  const int r0 = blockIdx.y * 32;
  const size_t sl = (size_t)NN * NH;
#pragma unroll
  for (int d = 0; d < 32; d += 8) {
    const int rr = r0 + ty + d;
    const size_t idx = (size_t)rr * NH + c0 + tx;
    float s = 0.f;
#pragma unroll
    for (int z = 0; z < SPLITZ; ++z) s += Qp[idx + (size_t)z * sl];
    const float q = drow[rr] * s;
    Q1[idx] = q;
    tile[ty + d][tx] = dcol[rr] * q;
  }
  __syncthreads();
#pragma unroll
  for (int d = 0; d < 32; d += 8)
    B2t[(size_t)(c0 + ty + d) * NN + r0 + tx] = f2bf(tile[tx][ty + d]);
}

// ---- fused: h = relu(0.5P - 0.5Q1 - drow .* sum(Hp)) in regs; R = h@W2; B3 ----
// block b covers rows 4b..4b+3: wave w = row 4b+w, lane covers cols lane*4..+3.
__global__ __launch_bounds__(256) void r3r_k(const float* __restrict__ Hp,
                                             const float* __restrict__ P,
                                             const float* __restrict__ Q1,
                                             const float* __restrict__ drow,
                                             const float* __restrict__ W2,
                                             const float* __restrict__ dcol,
                                             float* __restrict__ R,
                                             float* __restrict__ B3) {
  const int w = threadIdx.x >> 6, lane = threadIdx.x & 63;
  const int i = blockIdx.x * 4 + w;
  const size_t base = (size_t)i * NH + lane * 4;
  const size_t sl = (size_t)NN * NH;
  float4 s = make_float4(0.f, 0.f, 0.f, 0.f);
#pragma unroll
  for (int z = 0; z < SPLITZ; ++z) {
    float4 v = *(const float4*)(Hp + base + (size_t)z * sl);
    s.x += v.x; s.y += v.y; s.z += v.z; s.w += v.w;
  }
  float4 p = *(const float4*)(P + base);
  float4 q = *(const float4*)(Q1 + base);
  const float dr = drow[i];
  const float h0 = fmaxf(0.5f * p.x - 0.5f * q.x - dr * s.x, 0.f);
  const float h1 = fmaxf(0.5f * p.y - 0.5f * q.y - dr * s.y, 0.f);
  const float h2 = fmaxf(0.5f * p.z - 0.5f * q.z - dr * s.z, 0.f);
  const float h3 = fmaxf(0.5f * p.w - 0.5f * q.w - dr * s.w, 0.f);
  float4 w01 = *(const float4*)(W2 + lane * 8);
  float4 w23 = *(const float4*)(W2 + lane * 8 + 4);
  float a0 = h0 * w01.x + h1 * w01.z + h2 * w23.x + h3 * w23.z;
  float a1 = h0 * w01.y + h1 * w01.w + h2 * w23.y + h3 * w23.w;
#pragma unroll
  for (int off = 32; off > 0; off >>= 1) {
    a0 += __shfl_down(a0, off, 64);
    a1 += __shfl_down(a1, off, 64);
  }
  if (lane == 0) {
    R[i * 2] = a0;
    R[i * 2 + 1] = a1;
    const float dc = dcol[i];
    B3[i * 2] = dc * a0;
    B3[i * 2 + 1] = dc * a1;
  }
}

// ---- row GEMV over adjb (bf16) with 2-wide fp32 B; fused epilogues ----
__global__ __launch_bounds__(256) void gemv_k(
    const u16* __restrict__ adjb, const float* __restrict__ B,
    const float* __restrict__ drow, const float* __restrict__ dcol,
    const float* __restrict__ Rin, const float* __restrict__ S1in,
    const float* __restrict__ b2, float* __restrict__ S1out,
    float* __restrict__ B4, float* __restrict__ outp, int mode) {
  const int i = blockIdx.x;
  const int t = threadIdx.x;
  float a0 = 0.f, a1 = 0.f;
#pragma unroll
  for (int c = 0; c < 4; ++c) {
    const int col = c * 2048 + t * 8;
    uint4 av = *(const uint4*)(adjb + (size_t)i * NN + col);
    const u32* aw = (const u32*)&av;
    float bv[16];
    *(float4*)(bv) = *(const float4*)(B + col * 2);
    *(float4*)(bv + 4) = *(const float4*)(B + col * 2 + 4);
    *(float4*)(bv + 8) = *(const float4*)(B + col * 2 + 8);
    *(float4*)(bv + 12) = *(const float4*)(B + col * 2 + 12);
#pragma unroll
    for (int j = 0; j < 8; ++j) {
      const u32 a = aw[j >> 1];
      const float aval = bf2f((j & 1) ? (a >> 16) : (a & 0xffffu));
      a0 += aval * bv[2 * j];
      a1 += aval * bv[2 * j + 1];
    }
  }
#pragma unroll
  for (int off = 32; off > 0; off >>= 1) {
    a0 += __shfl_down(a0, off, 64);
    a1 += __shfl_down(a1, off, 64);
  }
  __shared__ float red[8];
  const int w = t >> 6, lane = t & 63;
  if (lane == 0) { red[w] = a0; red[4 + w] = a1; }
  __syncthreads();
  if (t == 0) {
    float s0 = (red[0] + red[1]) + (red[2] + red[3]);
    float s1 = (red[4] + red[5]) + (red[6] + red[7]);
    const float dr = drow[i];
    s0 *= dr; s1 *= dr;
    if (mode == 0) {  // S1 = d_row .* (adj@B3); B4 = d_col .* S1
      S1out[i * 2] = s0;
      S1out[i * 2 + 1] = s1;
      const float dc = dcol[i];
      B4[i * 2] = dc * s0;
      B4[i * 2 + 1] = dc * s1;
    } else {  // logits = 0.5R - 0.5S1 - S2 + b2; log_softmax
      const float l0 = 0.5f * Rin[i * 2] - 0.5f * S1in[i * 2] - s0 + b2[0];
      const float l1 = 0.5f * Rin[i * 2 + 1] - 0.5f * S1in[i * 2 + 1] - s1 + b2[1];
      const float m = fmaxf(l0, l1);
      const float lse = m + logf(__expf(l0 - m) + __expf(l1 - m));
      outp[i * 2] = l0 - lse;
      outp[i * 2 + 1] = l1 - lse;
    }
  }
}

extern "C" void kernel_launch(void* const* d_in, const int* in_sizes, int n_in,
                              void* d_out, int out_size, void* d_ws, size_t ws_size,
                              hipStream_t stream) {
  (void)in_sizes; (void)n_in; (void)out_size; (void)ws_size;
  const float* x   = (const float*)d_in[0];
  const float* adj = (const float*)d_in[1];
  const float* W1  = (const float*)d_in[2];
  const float* W2  = (const float*)d_in[3];
  const float* b2  = (const float*)d_in[4];
  float* outp = (float*)d_out;

  char* ws = (char*)d_ws;
  size_t off = 0;
  auto alloc = [&](size_t bytes) -> char* {
    char* p = ws + off;
    off += (bytes + 255) & ~(size_t)255;
    return p;
  };
  u16* adjb  = (u16*)alloc((size_t)NN * NN * 2);             // 134 MB
  u16* xb    = (u16*)alloc((size_t)NN * NF * 2);             // 8.4 MB
  u16* W1t   = (u16*)alloc((size_t)NH * NF * 2);             // 0.26 MB
  float* rowp = (float*)alloc((size_t)4 * NN * 4);           // 128 KB
  float* colp = (float*)alloc((size_t)RB * NN * 4);          // 8 MB
  float* drow = (float*)alloc((size_t)NN * 4);
  float* dcol = (float*)alloc((size_t)NN * 4);
  float* P   = (float*)alloc((size_t)NN * NH * 4);           // 8.4 MB
  u16* B1t   = (u16*)alloc((size_t)NH * NN * 2);             // 4.2 MB
  float* Qp  = (float*)alloc((size_t)SPLITZ * NN * NH * 4);  // 67 MB (reused as Hp)
  float* Q1  = (float*)alloc((size_t)NN * NH * 4);           // 8.4 MB
  u16* B2t   = (u16*)alloc((size_t)NH * NN * 2);             // 4.2 MB
  float* R   = (float*)alloc((size_t)NN * 2 * 4);
  float* B3  = (float*)alloc((size_t)NN * 2 * 4);
  float* S1  = (float*)alloc((size_t)NN * 2 * 4);
  float* B4  = (float*)alloc((size_t)NN * 2 * 4);
  float* Hp  = Qp;  // alias: Qp consumed by r2_k before second gemm writes Hp

  // xb/W1t first (feeds the P-section of mega_k)
  convxw1_k<<<2176, 256, 0, stream>>>(x, xb, W1, W1t);
  // conv_adj (1024 blocks) || P = xb@W1t (128 blocks)
  mega_k<<<1152, 256, 0, stream>>>(adj, adjb, rowp, colp, xb, W1t, P);
  reduce_sums_k<<<NN / 256, 256, 0, stream>>>(rowp, colp, drow, dcol);
  t1_k<<<dim3(8, 256), 256, 0, stream>>>(P, dcol, B1t);

  // Qp[z] = partial adj@B1 (256x256 tiles, ring pipeline)
  gemm256r_k<<<dim3(32, SPLITZ), 512, 0, stream>>>(adjb, B1t, NN / SPLITZ, Qp);
  r2_k<<<dim3(8, 256), 256, 0, stream>>>(Qp, drow, dcol, Q1, B2t);

  // Hp[z] = partial adj@B2
  gemm256r_k<<<dim3(32, SPLITZ), 512, 0, stream>>>(adjb, B2t, NN / SPLITZ, Hp);

  // h = relu(0.5P - 0.5Q1 - drow.*sum(Hp)); R = h@W2; B3 = dcol.*R
  r3r_k<<<NN / 4, 256, 0, stream>>>(Hp, P, Q1, drow, W2, dcol, R, B3);

  gemv_k<<<NN, 256, 0, stream>>>(adjb, B3, drow, dcol, nullptr, nullptr, nullptr, S1, B4, nullptr, 0);
  gemv_k<<<NN, 256, 0, stream>>>(adjb, B4, drow, dcol, R, S1, b2, nullptr, nullptr, outp, 1);
}